// Round 12
// baseline (41.867 us; speedup 1.0000x reference)
//
#include <hip/hip_runtime.h>
#include <hip/hip_bf16.h>

typedef unsigned short ushortT;
typedef __attribute__((ext_vector_type(8))) short bf16x8;
typedef __attribute__((ext_vector_type(4))) float f32x4;

#define N_NODES 384
#define KNBR 60
#define SUBK 20
#define NEDGE (N_NODES * KNBR)
#define EPSC 1e-8f
#define INV_SQRT_CZ 0.08838834764831845f   // 1/sqrt(128), folded into Wp1 q-cols
#define MU_STEP (20.0f / 63.0f)            // linspace(0,20,64) step
#define INV_MU_STEP (63.0f / 20.0f)
#define INV_SIGMA 3.2f                     // 1/(20/64)

__device__ __forceinline__ float bflo(unsigned int u) { return __uint_as_float(u << 16); }
__device__ __forceinline__ float bfhi(unsigned int u) { return __uint_as_float(u & 0xffff0000u); }
__device__ __forceinline__ ushortT f2bu(float v) {  // f32 -> bf16 bits, RNE
  union { float f; unsigned int u; } c;
  c.f = v;
  return (ushortT)((c.u + 0x7fffu + ((c.u >> 16) & 1u)) >> 16);
}
__device__ __forceinline__ unsigned int pack2bf(float x, float y) {
  return (unsigned int)f2bu(x) | ((unsigned int)f2bu(y) << 16);
}
__device__ __forceinline__ ushortT f2h(float x) {
  _Float16 h = (_Float16)x;
  return __builtin_bit_cast(ushortT, h);
}
__device__ __forceinline__ float h2f(ushortT u) {
  return (float)__builtin_bit_cast(_Float16, u);
}

// Fused prep: blocks 0..95 = gate projection; blocks 96..351 = weight packing
// (q-columns pre-scaled by 1/sqrt(c_z)) + bias concat.
__global__ __launch_bounds__(256) void prep_kernel(
    const float* __restrict__ nf, const float* __restrict__ Wg, float* __restrict__ g,
    const float* __restrict__ Wqk, const float* __restrict__ bqk,
    const float* __restrict__ Wv, const float* __restrict__ bv,
    const float* __restrict__ Wout,
    ushortT* __restrict__ Wp1, ushortT* __restrict__ Wp2, float* __restrict__ bc) {
  int b = blockIdx.x, tid = threadIdx.x;
  if (b < 96) {
    int n = b * 4 + (tid >> 6), t = tid & 63;
    float a = nf[n * 128 + t];
    float bb = nf[n * 128 + 64 + t];
    float acc[8];
#pragma unroll
    for (int h = 0; h < 4; ++h) {
      acc[h]     = a * Wg[t * 4 + h]         + bb * Wg[(t + 64) * 4 + h];
      acc[4 + h] = a * Wg[(128 + t) * 4 + h] + bb * Wg[(192 + t) * 4 + h];
    }
#pragma unroll
    for (int i = 0; i < 8; ++i)
#pragma unroll
      for (int off = 32; off >= 1; off >>= 1) acc[i] += __shfl_xor(acc[i], off, 64);
    if (t == 0) {
#pragma unroll
      for (int i = 0; i < 8; ++i) g[n * 8 + i] = acc[i];
    }
  } else {
    int i = (b - 96) * 256 + tid;  // 65536 total
    if (i < 49152) {
      int j = i & 7, l = (i >> 3) & 63, t = (i >> 9) & 3;
      int nt = (i >> 11) % 12, ny = (i >> 11) / 12;
      int nn = ny * 192 + nt * 16 + (l & 15);
      int k = t * 32 + (l >> 4) * 8 + j;
      float v = (nn < 256) ? Wqk[k * 256 + nn] : Wv[k * 128 + (nn - 256)];
      if (nn < 128) v *= INV_SQRT_CZ;   // q columns pre-scaled
      Wp1[i] = f2bu(v);
    } else {
      int i2 = i - 49152;  // 16384
      int j = i2 & 7, l = (i2 >> 3) & 63, t = (i2 >> 9) & 3, nt = (i2 >> 11);
      int nn = nt * 16 + (l & 15);
      int k = t * 32 + (l >> 4) * 8 + j;
      Wp2[i2] = f2bu(Wout[k * 128 + nn]);
    }
    if (i < 384) {
      float v = (i < 256) ? bqk[i] : bv[i - 256];
      if (i < 128) v *= INV_SQRT_CZ;
      bc[i] = v;
    }
  }
}

// One block per node, 512 threads (8 waves). Wave-specialized overlap region:
// waves 0-3 do qkv col-tiles T0..19 (rows = (w&3)*16+lr); waves 4-7 stage trs/gg,
// run the full bias precompute, then finish tiles T20..23. Weights direct from
// global (L2-resident). kvb c-major conflict-free; single-pass softmax.
__global__ __launch_bounds__(512, 4) void fused_kernel(
    const float* __restrict__ ef, const ushortT* __restrict__ Wp1,
    const ushortT* __restrict__ Wp2, const float* __restrict__ bc,
    const float* __restrict__ bout, const float* __restrict__ g,
    const float* __restrict__ node_trans, const int* __restrict__ edge_index,
    const int* __restrict__ sub_idx, const float* __restrict__ W_db,
    const float* __restrict__ b_db, const float* __restrict__ b_gate,
    float* __restrict__ outp) {
  __shared__ __align__(16) ushortT kvb[KNBR * 256];     // 30720 B
  __shared__ __align__(16) ushortT updq[64 * 136];      // 17408 B (q then upd)
  __shared__ __align__(16) ushortT biasb[KNBR * SUBK * 4];  // 9600 B, f16
  __shared__ ushortT sub_lds[KNBR * SUBK];              // 2400 B
  __shared__ float trs[KNBR * 3];                       // 720 B
  __shared__ float gg[KNBR * 8];                        // 1920 B

  int n = blockIdx.x, tid = threadIdx.x;
  int e0 = n * KNBR;
  int w = tid >> 6, l = tid & 63;
  int lr = l & 15, lc = l >> 4;
  int rowA = (w & 3) * 16 + lr;          // 0..63 (rows 60..63 pad)
  int rowAc = min(rowA, KNBR - 1);

  // ---- phase 0: trs/gg staged by waves 4 and 5 ----
  if (w == 4 && l < KNBR) {
    int dst = edge_index[e0 + l];
#pragma unroll
    for (int c = 0; c < 3; ++c) trs[l * 3 + c] = node_trans[dst * 3 + c];
  }
  if (w == 5 && l < KNBR) {
    int dst = edge_index[e0 + l];
#pragma unroll
    for (int i = 0; i < 8; ++i) gg[l * 8 + i] = g[dst * 8 + i];
  }
  __syncthreads();  // barrier 1: trs/gg visible to waves 4-7

  // A fragments (all waves; bias waves use them for T20..23)
  bf16x8 afrag[4];
#pragma unroll
  for (int t = 0; t < 4; ++t) {
    const float* ap = ef + (size_t)(e0 + rowAc) * 128 + t * 32 + lc * 8;
    float4 lo = *(const float4*)ap;
    float4 hi = *(const float4*)(ap + 4);
    bf16x8 a;
    a[0] = (short)f2bu(lo.x); a[1] = (short)f2bu(lo.y);
    a[2] = (short)f2bu(lo.z); a[3] = (short)f2bu(lo.w);
    a[4] = (short)f2bu(hi.x); a[5] = (short)f2bu(hi.y);
    a[6] = (short)f2bu(hi.z); a[7] = (short)f2bu(hi.w);
    afrag[t] = a;
  }

#define TILE_BODY(T)                                                                   \
  {                                                                                    \
    f32x4 acc = {0.f, 0.f, 0.f, 0.f};                                                  \
    _Pragma("unroll") for (int t = 0; t < 4; ++t) {                                    \
      bf16x8 bfrag = *(const bf16x8*)(Wp1 + (((T) * 4 + t) * 64 + l) * 8);             \
      acc = __builtin_amdgcn_mfma_f32_16x16x32_bf16(bfrag, afrag[t], acc, 0, 0, 0);    \
    }                                                                                  \
    int col0 = (T) * 16 + lc * 4;                                                      \
    float4 bi = *(const float4*)(bc + col0);                                           \
    float o0 = acc[0] + bi.x, o1 = acc[1] + bi.y;                                      \
    float o2 = acc[2] + bi.z, o3 = acc[3] + bi.w;                                      \
    if ((T) < 8) {                                                                     \
      uint2 o;                                                                         \
      o.x = pack2bf(o0, o1);                                                           \
      o.y = pack2bf(o2, o3);                                                           \
      *(uint2*)(updq + rowA * 136 + col0) = o;                                         \
    } else if (rowA < KNBR) {                                                          \
      uint2 o;                                                                         \
      o.x = pack2bf(o0, o1);                                                           \
      o.y = pack2bf(o2, o3);                                                           \
      int colk = col0 - 128;                                                           \
      int base_b = (colk & 128) << 1;                                                  \
      int d = colk & 127;                                                              \
      int inner = ((d >> 3) & 1) * 128 + (((d >> 4) * 16) ^ ((rowA & 7) << 4)) +       \
                  (d & 7) * 2;                                                         \
      *(uint2*)((char*)kvb + rowA * 512 + base_b + inner) = o;                         \
    }                                                                                  \
  }

  if (w < 4) {
    // ---- waves 0-3: qkv tiles T0..19 ----
#pragma unroll
    for (int T = 0; T < 20; ++T) TILE_BODY(T)
  } else {
    // ---- waves 4-7: bias precompute (1200 pairs / 256 threads) ----
    float4 bgv = *(const float4*)b_gate;
    float4 bdbv = *(const float4*)b_db;
    for (int p = tid - 256; p < KNBR * SUBK; p += 256) {
      int kl = p / SUBK, s = p - kl * SUBK;
      int j = sub_idx[(size_t)(e0 + kl) * SUBK + s];
      sub_lds[p] = (ushortT)j;
      float dx = trs[kl * 3 + 0] - trs[j * 3 + 0] + EPSC;
      float dy = trs[kl * 3 + 1] - trs[j * 3 + 1] + EPSC;
      float dz = trs[kl * 3 + 2] - trs[j * 3 + 2] + EPSC;
      float dist = sqrtf(dx * dx + dy * dy + dz * dz);
      int r0 = (int)(dist * INV_MU_STEP + 0.5f);
      int rlo = max(r0 - 4, 0), rhi = min(r0 + 4, 63);
      float a0 = 0.f, a1 = 0.f, a2 = 0.f, a3 = 0.f;
      for (int r = rlo; r <= rhi; ++r) {
        float t = (dist - r * MU_STEP) * INV_SIGMA;
        float e = __expf(-t * t);
        float4 wv = ((const float4*)W_db)[r];
        a0 += e * wv.x; a1 += e * wv.y; a2 += e * wv.z; a3 += e * wv.w;
      }
      float g1 = gg[kl * 8 + 0] + gg[j * 8 + 4 + 0] + bgv.x;
      float g2 = gg[kl * 8 + 1] + gg[j * 8 + 4 + 1] + bgv.y;
      float g3 = gg[kl * 8 + 2] + gg[j * 8 + 4 + 2] + bgv.z;
      float g4 = gg[kl * 8 + 3] + gg[j * 8 + 4 + 3] + bgv.w;
      biasb[p * 4 + 0] = f2h((a0 + bdbv.x) / (1.0f + __expf(-g1)));
      biasb[p * 4 + 1] = f2h((a1 + bdbv.y) / (1.0f + __expf(-g2)));
      biasb[p * 4 + 2] = f2h((a2 + bdbv.z) / (1.0f + __expf(-g3)));
      biasb[p * 4 + 3] = f2h((a3 + bdbv.w) / (1.0f + __expf(-g4)));
    }
    // ---- then finish qkv tiles T20..23 ----
#pragma unroll
    for (int T = 20; T < 24; ++T) TILE_BODY(T)
  }
  __syncthreads();  // barrier 2: kvb + q(updq) + biasb + sub_lds visible

  // ---- phase 3: attention, single pass (q pre-scaled; logits bounded) ----
  int row3 = tid >> 3, h = (tid >> 1) & 3, dh = tid & 1;
  int row3c = min(row3, KNBR - 1);
  int hdo = (h * 2 + dh) * 16;
  const char* kvbase = (const char*)kvb;
  float q0, q1, q2, q3, q4, q5, q6, q7, q8, q9, q10, q11, q12, q13, q14, q15;
  {
    const ushortT* qp = updq + row3 * 136 + h * 32 + dh * 16;
    uint4 u0 = *(const uint4*)qp;
    uint4 u1 = *(const uint4*)(qp + 8);
    q0 = bflo(u0.x); q1 = bfhi(u0.x); q2 = bflo(u0.y); q3 = bfhi(u0.y);
    q4 = bflo(u0.z); q5 = bfhi(u0.z); q6 = bflo(u0.w); q7 = bfhi(u0.w);
    q8 = bflo(u1.x); q9 = bfhi(u1.x); q10 = bflo(u1.y); q11 = bfhi(u1.y);
    q12 = bflo(u1.z); q13 = bfhi(u1.z); q14 = bflo(u1.w); q15 = bfhi(u1.w);
  }
  float den = 0.f;
  float v0 = 0.f, v1 = 0.f, v2 = 0.f, v3 = 0.f, v4 = 0.f, v5 = 0.f, v6 = 0.f, v7 = 0.f;
  float v8 = 0.f, v9 = 0.f, v10 = 0.f, v11 = 0.f, v12 = 0.f, v13 = 0.f, v14 = 0.f, v15 = 0.f;
#pragma unroll 4
  for (int s = 0; s < SUBK; ++s) {
    int j = sub_lds[row3c * SUBK + s];
    int off = hdo ^ ((j & 7) << 4);
    const char* kr = kvbase + j * 512;
    uint4 k0 = *(const uint4*)(kr + off);
    uint4 k1 = *(const uint4*)(kr + 128 + off);
    float dot = q0 * bflo(k0.x) + q1 * bfhi(k0.x) + q2 * bflo(k0.y) + q3 * bfhi(k0.y) +
                q4 * bflo(k0.z) + q5 * bfhi(k0.z) + q6 * bflo(k0.w) + q7 * bfhi(k0.w) +
                q8 * bflo(k1.x) + q9 * bfhi(k1.x) + q10 * bflo(k1.y) + q11 * bfhi(k1.y) +
                q12 * bflo(k1.z) + q13 * bfhi(k1.z) + q14 * bflo(k1.w) + q15 * bfhi(k1.w);
    dot += __shfl_xor(dot, 1);
    float p = __expf(dot + h2f(biasb[(row3c * SUBK + s) * 4 + h]));
    den += p;
    uint4 w0 = *(const uint4*)(kr + 256 + off);
    uint4 w1 = *(const uint4*)(kr + 384 + off);
    v0 += p * bflo(w0.x); v1 += p * bfhi(w0.x); v2 += p * bflo(w0.y); v3 += p * bfhi(w0.y);
    v4 += p * bflo(w0.z); v5 += p * bfhi(w0.z); v6 += p * bflo(w0.w); v7 += p * bfhi(w0.w);
    v8 += p * bflo(w1.x); v9 += p * bfhi(w1.x); v10 += p * bflo(w1.y); v11 += p * bfhi(w1.y);
    v12 += p * bflo(w1.z); v13 += p * bfhi(w1.z); v14 += p * bflo(w1.w); v15 += p * bfhi(w1.w);
  }
  float inv = 1.0f / den;
  {
    uint4 o;
    o.x = pack2bf(v0 * inv, v1 * inv);
    o.y = pack2bf(v2 * inv, v3 * inv);
    o.z = pack2bf(v4 * inv, v5 * inv);
    o.w = pack2bf(v6 * inv, v7 * inv);
    *(uint4*)(updq + row3 * 136 + h * 32 + dh * 16) = o;
    uint4 o2;
    o2.x = pack2bf(v8 * inv, v9 * inv);
    o2.y = pack2bf(v10 * inv, v11 * inv);
    o2.z = pack2bf(v12 * inv, v13 * inv);
    o2.w = pack2bf(v14 * inv, v15 * inv);
    *(uint4*)(updq + row3 * 136 + h * 32 + dh * 16 + 8) = o2;
  }
  __syncthreads();  // barrier 3: upd visible

  // ---- phase 4: out projection, 4 col-tiles per group ----
  bf16x8 af2[4];
#pragma unroll
  for (int t = 0; t < 4; ++t)
    af2[t] = *(const bf16x8*)(updq + rowA * 136 + t * 32 + lc * 8);
  int T4base = (tid >> 8) * 4;
#pragma unroll
  for (int Ti = 0; Ti < 4; ++Ti) {
    int T = T4base + Ti;
    f32x4 acc = {0.f, 0.f, 0.f, 0.f};
#pragma unroll
    for (int t = 0; t < 4; ++t) {
      bf16x8 bfrag = *(const bf16x8*)(Wp2 + ((T * 4 + t) * 64 + l) * 8);
      acc = __builtin_amdgcn_mfma_f32_16x16x32_bf16(bfrag, af2[t], acc, 0, 0, 0);
    }
    if (rowA < KNBR) {
      int col0 = T * 16 + lc * 4;
      float4 bi = *(const float4*)(bout + col0);
      float4 o;
      o.x = acc[0] + bi.x; o.y = acc[1] + bi.y;
      o.z = acc[2] + bi.z; o.w = acc[3] + bi.w;
      *(float4*)(outp + (size_t)(e0 + rowA) * 128 + col0) = o;
    }
  }
#undef TILE_BODY
}

extern "C" void kernel_launch(void* const* d_in, const int* in_sizes, int n_in, void* d_out,
                              int out_size, void* d_ws, size_t ws_size, hipStream_t stream) {
  const float* nf  = (const float*)d_in[0];
  const float* nt  = (const float*)d_in[1];
  const float* ef  = (const float*)d_in[2];
  const int*   ei  = (const int*)d_in[3];
  const int*   si  = (const int*)d_in[4];
  const float* Wg  = (const float*)d_in[5];
  const float* bg  = (const float*)d_in[6];
  const float* Wdb = (const float*)d_in[7];
  const float* bdb = (const float*)d_in[8];
  const float* Wqk = (const float*)d_in[9];
  const float* bqk = (const float*)d_in[10];
  const float* Wv  = (const float*)d_in[11];
  const float* bv  = (const float*)d_in[12];
  const float* Wout = (const float*)d_in[13];
  const float* bout = (const float*)d_in[14];
  float* out = (float*)d_out;  // f32 output

  float* g      = (float*)d_ws;                 // 3072 f32
  float* bc     = g + 3072;                     // 384 f32
  ushortT* Wp1  = (ushortT*)(bc + 384);         // 49152 bf16
  ushortT* Wp2  = Wp1 + 49152;                  // 16384 bf16

  prep_kernel<<<dim3(352), dim3(256), 0, stream>>>(nf, Wg, g, Wqk, bqk, Wv, bv, Wout,
                                                   Wp1, Wp2, bc);
  fused_kernel<<<dim3(N_NODES), dim3(512), 0, stream>>>(ef, Wp1, Wp2, bc, bout, g, nt, ei, si,
                                                        Wdb, bdb, bg, out);
}

// Round 13
// 40.905 us; speedup vs baseline: 1.0235x; 1.0235x over previous
//
#include <hip/hip_runtime.h>
#include <hip/hip_bf16.h>

typedef unsigned short ushortT;
typedef __attribute__((ext_vector_type(8))) short bf16x8;
typedef __attribute__((ext_vector_type(4))) float f32x4;

#define N_NODES 384
#define KNBR 60
#define SUBK 20
#define NEDGE (N_NODES * KNBR)
#define EPSC 1e-8f
#define INV_SQRT_CZ 0.08838834764831845f   // 1/sqrt(128), folded into Wp1 q-cols
#define MU_STEP (20.0f / 63.0f)            // linspace(0,20,64) step
#define INV_MU_STEP (63.0f / 20.0f)
#define INV_SIGMA 3.2f                     // 1/(20/64)

__device__ __forceinline__ float bflo(unsigned int u) { return __uint_as_float(u << 16); }
__device__ __forceinline__ float bfhi(unsigned int u) { return __uint_as_float(u & 0xffff0000u); }
__device__ __forceinline__ ushortT f2bu(float v) {  // f32 -> bf16 bits, RNE
  union { float f; unsigned int u; } c;
  c.f = v;
  return (ushortT)((c.u + 0x7fffu + ((c.u >> 16) & 1u)) >> 16);
}
__device__ __forceinline__ unsigned int pack2bf(float x, float y) {
  return (unsigned int)f2bu(x) | ((unsigned int)f2bu(y) << 16);
}
__device__ __forceinline__ ushortT f2h(float x) {
  _Float16 h = (_Float16)x;
  return __builtin_bit_cast(ushortT, h);
}
__device__ __forceinline__ float h2f(ushortT u) {
  return (float)__builtin_bit_cast(_Float16, u);
}

// Fused prep: blocks 0..95 = gate projection; blocks 96..351 = weight packing
// (q-columns pre-scaled by 1/sqrt(c_z)) + bias concat.
__global__ __launch_bounds__(256) void prep_kernel(
    const float* __restrict__ nf, const float* __restrict__ Wg, float* __restrict__ g,
    const float* __restrict__ Wqk, const float* __restrict__ bqk,
    const float* __restrict__ Wv, const float* __restrict__ bv,
    const float* __restrict__ Wout,
    ushortT* __restrict__ Wp1, ushortT* __restrict__ Wp2, float* __restrict__ bc) {
  int b = blockIdx.x, tid = threadIdx.x;
  if (b < 96) {
    int n = b * 4 + (tid >> 6), t = tid & 63;
    float a = nf[n * 128 + t];
    float bb = nf[n * 128 + 64 + t];
    float acc[8];
#pragma unroll
    for (int h = 0; h < 4; ++h) {
      acc[h]     = a * Wg[t * 4 + h]         + bb * Wg[(t + 64) * 4 + h];
      acc[4 + h] = a * Wg[(128 + t) * 4 + h] + bb * Wg[(192 + t) * 4 + h];
    }
#pragma unroll
    for (int i = 0; i < 8; ++i)
#pragma unroll
      for (int off = 32; off >= 1; off >>= 1) acc[i] += __shfl_xor(acc[i], off, 64);
    if (t == 0) {
#pragma unroll
      for (int i = 0; i < 8; ++i) g[n * 8 + i] = acc[i];
    }
  } else {
    int i = (b - 96) * 256 + tid;  // 65536 total
    if (i < 49152) {
      int j = i & 7, l = (i >> 3) & 63, t = (i >> 9) & 3;
      int nt = (i >> 11) % 12, ny = (i >> 11) / 12;
      int nn = ny * 192 + nt * 16 + (l & 15);
      int k = t * 32 + (l >> 4) * 8 + j;
      float v = (nn < 256) ? Wqk[k * 256 + nn] : Wv[k * 128 + (nn - 256)];
      if (nn < 128) v *= INV_SQRT_CZ;   // q columns pre-scaled
      Wp1[i] = f2bu(v);
    } else {
      int i2 = i - 49152;  // 16384
      int j = i2 & 7, l = (i2 >> 3) & 63, t = (i2 >> 9) & 3, nt = (i2 >> 11);
      int nn = nt * 16 + (l & 15);
      int k = t * 32 + (l >> 4) * 8 + j;
      Wp2[i2] = f2bu(Wout[k * 128 + nn]);
    }
    if (i < 384) {
      float v = (i < 256) ? bqk[i] : bv[i - 256];
      if (i < 128) v *= INV_SQRT_CZ;
      bc[i] = v;
    }
  }
}

// One block per node, 512 threads (8 waves, two 4-wave groups). Weights direct
// from global (L2-resident), B-fragments register-double-buffered (prefetch-1).
// kvb c-major conflict-free; single-pass softmax; q pre-scaled in Wp1.
__global__ __launch_bounds__(512, 4) void fused_kernel(
    const float* __restrict__ ef, const ushortT* __restrict__ Wp1,
    const ushortT* __restrict__ Wp2, const float* __restrict__ bc,
    const float* __restrict__ bout, const float* __restrict__ g,
    const float* __restrict__ node_trans, const int* __restrict__ edge_index,
    const int* __restrict__ sub_idx, const float* __restrict__ W_db,
    const float* __restrict__ b_db, const float* __restrict__ b_gate,
    float* __restrict__ outp) {
  __shared__ __align__(16) ushortT kvb[KNBR * 256];     // 30720 B
  __shared__ __align__(16) ushortT updq[64 * 136];      // 17408 B (q then upd)
  __shared__ __align__(16) ushortT biasb[KNBR * SUBK * 4];  // 9600 B, f16
  __shared__ ushortT sub_lds[KNBR * SUBK];              // 2400 B
  __shared__ float trs[KNBR * 3];                       // 720 B
  __shared__ float gg[KNBR * 8];                        // 1920 B

  int n = blockIdx.x, tid = threadIdx.x;
  int e0 = n * KNBR;
  int w = tid >> 6, l = tid & 63;
  int lr = l & 15, lc = l >> 4;
  int rowA = (w & 3) * 16 + lr;          // 0..63 (rows 60..63 pad)
  int rowAc = min(rowA, KNBR - 1);
  int Tbase = (tid >> 8) * 12;

  // ---- phase 0: stage trs/gg (no barrier; consumed after barrier A) ----
  if (tid < KNBR) {
    int dst = edge_index[e0 + tid];
#pragma unroll
    for (int c = 0; c < 3; ++c) trs[tid * 3 + c] = node_trans[dst * 3 + c];
#pragma unroll
    for (int i = 0; i < 8; ++i) gg[tid * 8 + i] = g[dst * 8 + i];
  }

  // prefetch first B-tile (weight L2/HBM miss overlaps ef miss below)
  bf16x8 bcur[4], bnxt[4];
#pragma unroll
  for (int t = 0; t < 4; ++t)
    bcur[t] = *(const bf16x8*)(Wp1 + ((Tbase * 4 + t) * 64 + l) * 8);

  // A fragments from ef (f32 -> bf16)
  bf16x8 afrag[4];
#pragma unroll
  for (int t = 0; t < 4; ++t) {
    const float* ap = ef + (size_t)(e0 + rowAc) * 128 + t * 32 + lc * 8;
    float4 lo = *(const float4*)ap;
    float4 hi = *(const float4*)(ap + 4);
    bf16x8 a;
    a[0] = (short)f2bu(lo.x); a[1] = (short)f2bu(lo.y);
    a[2] = (short)f2bu(lo.z); a[3] = (short)f2bu(lo.w);
    a[4] = (short)f2bu(hi.x); a[5] = (short)f2bu(hi.y);
    a[6] = (short)f2bu(hi.z); a[7] = (short)f2bu(hi.w);
    afrag[t] = a;
  }

  // ---- phase 1: qkv projection, 12 tiles/group, prefetch-1 pipeline ----
#pragma unroll
  for (int Ti = 0; Ti < 12; ++Ti) {
    int T = Tbase + Ti;
    if (Ti < 11) {
#pragma unroll
      for (int t = 0; t < 4; ++t)
        bnxt[t] = *(const bf16x8*)(Wp1 + (((T + 1) * 4 + t) * 64 + l) * 8);
    }
    f32x4 acc = {0.f, 0.f, 0.f, 0.f};
#pragma unroll
    for (int t = 0; t < 4; ++t)
      acc = __builtin_amdgcn_mfma_f32_16x16x32_bf16(bcur[t], afrag[t], acc, 0, 0, 0);
    int col0 = T * 16 + lc * 4;
    float4 bi = *(const float4*)(bc + col0);
    float o0 = acc[0] + bi.x, o1 = acc[1] + bi.y;
    float o2 = acc[2] + bi.z, o3 = acc[3] + bi.w;
    uint2 o;
    o.x = pack2bf(o0, o1);
    o.y = pack2bf(o2, o3);
    if (T < 8) {  // q (pre-scaled) -> updq
      *(uint2*)(updq + rowA * 136 + col0) = o;
    } else if (rowA < KNBR) {  // k,v -> kvb (c-major, swizzled)
      int colk = col0 - 128;                  // 0..255
      int base_b = (colk & 128) << 1;         // 0 (K) or 256 (V)
      int d = colk & 127;
      int inner = ((d >> 3) & 1) * 128 + (((d >> 4) * 16) ^ ((rowA & 7) << 4)) + (d & 7) * 2;
      *(uint2*)((char*)kvb + rowA * 512 + base_b + inner) = o;
    }
#pragma unroll
    for (int t = 0; t < 4; ++t) bcur[t] = bnxt[t];
  }
  __syncthreads();  // barrier A: trs/gg + (phase 1 still needs nothing) visible

  // ---- phase 2: bias precompute (dist + truncated RBF + gate) ----
  float4 bgv = *(const float4*)b_gate;
  float4 bdbv = *(const float4*)b_db;
  for (int p = tid; p < KNBR * SUBK; p += 512) {
    int kl = p / SUBK, s = p - kl * SUBK;
    int j = sub_idx[(size_t)(e0 + kl) * SUBK + s];
    sub_lds[p] = (ushortT)j;
    float dx = trs[kl * 3 + 0] - trs[j * 3 + 0] + EPSC;
    float dy = trs[kl * 3 + 1] - trs[j * 3 + 1] + EPSC;
    float dz = trs[kl * 3 + 2] - trs[j * 3 + 2] + EPSC;
    float dist = sqrtf(dx * dx + dy * dy + dz * dz);
    int r0 = (int)(dist * INV_MU_STEP + 0.5f);
    int rlo = max(r0 - 4, 0), rhi = min(r0 + 4, 63);
    float a0 = 0.f, a1 = 0.f, a2 = 0.f, a3 = 0.f;
    for (int r = rlo; r <= rhi; ++r) {
      float t = (dist - r * MU_STEP) * INV_SIGMA;
      float e = __expf(-t * t);
      float4 wv = ((const float4*)W_db)[r];
      a0 += e * wv.x; a1 += e * wv.y; a2 += e * wv.z; a3 += e * wv.w;
    }
    float g1 = gg[kl * 8 + 0] + gg[j * 8 + 4 + 0] + bgv.x;
    float g2 = gg[kl * 8 + 1] + gg[j * 8 + 4 + 1] + bgv.y;
    float g3 = gg[kl * 8 + 2] + gg[j * 8 + 4 + 2] + bgv.z;
    float g4 = gg[kl * 8 + 3] + gg[j * 8 + 4 + 3] + bgv.w;
    biasb[p * 4 + 0] = f2h((a0 + bdbv.x) / (1.0f + __expf(-g1)));
    biasb[p * 4 + 1] = f2h((a1 + bdbv.y) / (1.0f + __expf(-g2)));
    biasb[p * 4 + 2] = f2h((a2 + bdbv.z) / (1.0f + __expf(-g3)));
    biasb[p * 4 + 3] = f2h((a3 + bdbv.w) / (1.0f + __expf(-g4)));
  }
  __syncthreads();  // barrier B: kvb + q(updq) + biasb + sub_lds visible

  // ---- phase 3: attention, single pass (q pre-scaled; logits bounded) ----
  int row3 = tid >> 3, h = (tid >> 1) & 3, dh = tid & 1;
  int row3c = min(row3, KNBR - 1);
  int hdo = (h * 2 + dh) * 16;
  const char* kvbase = (const char*)kvb;
  float q0, q1, q2, q3, q4, q5, q6, q7, q8, q9, q10, q11, q12, q13, q14, q15;
  {
    const ushortT* qp = updq + row3 * 136 + h * 32 + dh * 16;
    uint4 u0 = *(const uint4*)qp;
    uint4 u1 = *(const uint4*)(qp + 8);
    q0 = bflo(u0.x); q1 = bfhi(u0.x); q2 = bflo(u0.y); q3 = bfhi(u0.y);
    q4 = bflo(u0.z); q5 = bfhi(u0.z); q6 = bflo(u0.w); q7 = bfhi(u0.w);
    q8 = bflo(u1.x); q9 = bfhi(u1.x); q10 = bflo(u1.y); q11 = bfhi(u1.y);
    q12 = bflo(u1.z); q13 = bfhi(u1.z); q14 = bflo(u1.w); q15 = bfhi(u1.w);
  }
  float den = 0.f;
  float v0 = 0.f, v1 = 0.f, v2 = 0.f, v3 = 0.f, v4 = 0.f, v5 = 0.f, v6 = 0.f, v7 = 0.f;
  float v8 = 0.f, v9 = 0.f, v10 = 0.f, v11 = 0.f, v12 = 0.f, v13 = 0.f, v14 = 0.f, v15 = 0.f;
#pragma unroll 4
  for (int s = 0; s < SUBK; ++s) {
    int j = sub_lds[row3c * SUBK + s];
    int off = hdo ^ ((j & 7) << 4);
    const char* kr = kvbase + j * 512;
    uint4 k0 = *(const uint4*)(kr + off);
    uint4 k1 = *(const uint4*)(kr + 128 + off);
    float dot = q0 * bflo(k0.x) + q1 * bfhi(k0.x) + q2 * bflo(k0.y) + q3 * bfhi(k0.y) +
                q4 * bflo(k0.z) + q5 * bfhi(k0.z) + q6 * bflo(k0.w) + q7 * bfhi(k0.w) +
                q8 * bflo(k1.x) + q9 * bfhi(k1.x) + q10 * bflo(k1.y) + q11 * bfhi(k1.y) +
                q12 * bflo(k1.z) + q13 * bfhi(k1.z) + q14 * bflo(k1.w) + q15 * bfhi(k1.w);
    dot += __shfl_xor(dot, 1);
    float p = __expf(dot + h2f(biasb[(row3c * SUBK + s) * 4 + h]));
    den += p;
    uint4 w0 = *(const uint4*)(kr + 256 + off);
    uint4 w1 = *(const uint4*)(kr + 384 + off);
    v0 += p * bflo(w0.x); v1 += p * bfhi(w0.x); v2 += p * bflo(w0.y); v3 += p * bfhi(w0.y);
    v4 += p * bflo(w0.z); v5 += p * bfhi(w0.z); v6 += p * bflo(w0.w); v7 += p * bfhi(w0.w);
    v8 += p * bflo(w1.x); v9 += p * bfhi(w1.x); v10 += p * bflo(w1.y); v11 += p * bfhi(w1.y);
    v12 += p * bflo(w1.z); v13 += p * bfhi(w1.z); v14 += p * bflo(w1.w); v15 += p * bfhi(w1.w);
  }
  float inv = 1.0f / den;
  {
    uint4 o;
    o.x = pack2bf(v0 * inv, v1 * inv);
    o.y = pack2bf(v2 * inv, v3 * inv);
    o.z = pack2bf(v4 * inv, v5 * inv);
    o.w = pack2bf(v6 * inv, v7 * inv);
    *(uint4*)(updq + row3 * 136 + h * 32 + dh * 16) = o;
    uint4 o2;
    o2.x = pack2bf(v8 * inv, v9 * inv);
    o2.y = pack2bf(v10 * inv, v11 * inv);
    o2.z = pack2bf(v12 * inv, v13 * inv);
    o2.w = pack2bf(v14 * inv, v15 * inv);
    *(uint4*)(updq + row3 * 136 + h * 32 + dh * 16 + 8) = o2;
  }
  __syncthreads();  // barrier C: upd visible

  // ---- phase 4: out projection, 4 tiles/group, prefetch-1 pipeline ----
  int T4base = (tid >> 8) * 4;
  bf16x8 af2[4];
#pragma unroll
  for (int t = 0; t < 4; ++t)
    af2[t] = *(const bf16x8*)(updq + rowA * 136 + t * 32 + lc * 8);
  bf16x8 c2[4], n2[4];
#pragma unroll
  for (int t = 0; t < 4; ++t)
    c2[t] = *(const bf16x8*)(Wp2 + ((T4base * 4 + t) * 64 + l) * 8);
#pragma unroll
  for (int Ti = 0; Ti < 4; ++Ti) {
    int T = T4base + Ti;
    if (Ti < 3) {
#pragma unroll
      for (int t = 0; t < 4; ++t)
        n2[t] = *(const bf16x8*)(Wp2 + (((T + 1) * 4 + t) * 64 + l) * 8);
    }
    f32x4 acc = {0.f, 0.f, 0.f, 0.f};
#pragma unroll
    for (int t = 0; t < 4; ++t)
      acc = __builtin_amdgcn_mfma_f32_16x16x32_bf16(c2[t], af2[t], acc, 0, 0, 0);
    if (rowA < KNBR) {
      int col0 = T * 16 + lc * 4;
      float4 bi = *(const float4*)(bout + col0);
      float4 o;
      o.x = acc[0] + bi.x; o.y = acc[1] + bi.y;
      o.z = acc[2] + bi.z; o.w = acc[3] + bi.w;
      *(float4*)(outp + (size_t)(e0 + rowA) * 128 + col0) = o;
    }
#pragma unroll
    for (int t = 0; t < 4; ++t) c2[t] = n2[t];
  }
}

extern "C" void kernel_launch(void* const* d_in, const int* in_sizes, int n_in, void* d_out,
                              int out_size, void* d_ws, size_t ws_size, hipStream_t stream) {
  const float* nf  = (const float*)d_in[0];
  const float* nt  = (const float*)d_in[1];
  const float* ef  = (const float*)d_in[2];
  const int*   ei  = (const int*)d_in[3];
  const int*   si  = (const int*)d_in[4];
  const float* Wg  = (const float*)d_in[5];
  const float* bg  = (const float*)d_in[6];
  const float* Wdb = (const float*)d_in[7];
  const float* bdb = (const float*)d_in[8];
  const float* Wqk = (const float*)d_in[9];
  const float* bqk = (const float*)d_in[10];
  const float* Wv  = (const float*)d_in[11];
  const float* bv  = (const float*)d_in[12];
  const float* Wout = (const float*)d_in[13];
  const float* bout = (const float*)d_in[14];
  float* out = (float*)d_out;  // f32 output

  float* g      = (float*)d_ws;                 // 3072 f32
  float* bc     = g + 3072;                     // 384 f32
  ushortT* Wp1  = (ushortT*)(bc + 384);         // 49152 bf16
  ushortT* Wp2  = Wp1 + 49152;                  // 16384 bf16

  prep_kernel<<<dim3(352), dim3(256), 0, stream>>>(nf, Wg, g, Wqk, bqk, Wv, bv, Wout,
                                                   Wp1, Wp2, bc);
  fused_kernel<<<dim3(N_NODES), dim3(512), 0, stream>>>(ef, Wp1, Wp2, bc, bout, g, nt, ei, si,
                                                        Wdb, bdb, bg, out);
}

// Round 14
// 40.531 us; speedup vs baseline: 1.0330x; 1.0092x over previous
//
#include <hip/hip_runtime.h>
#include <hip/hip_bf16.h>

typedef unsigned short ushortT;
typedef __attribute__((ext_vector_type(8))) short bf16x8;
typedef __attribute__((ext_vector_type(4))) float f32x4;
typedef __attribute__((ext_vector_type(2))) float f32x2;

#define N_NODES 384
#define KNBR 60
#define SUBK 20
#define NEDGE (N_NODES * KNBR)
#define EPSC 1e-8f
#define INV_SQRT_CZ 0.08838834764831845f   // 1/sqrt(128), folded into Wp1 q-cols
#define MU_STEP (20.0f / 63.0f)            // linspace(0,20,64) step
#define INV_MU_STEP (63.0f / 20.0f)
#define INV_SIGMA 3.2f                     // 1/(20/64)

__device__ __forceinline__ float bflo(unsigned int u) { return __uint_as_float(u << 16); }
__device__ __forceinline__ float bfhi(unsigned int u) { return __uint_as_float(u & 0xffff0000u); }
__device__ __forceinline__ f32x2 bfpair(unsigned int u) {
  f32x2 r;
  r.x = bflo(u);
  r.y = bfhi(u);
  return r;
}
__device__ __forceinline__ ushortT f2bu(float v) {  // f32 -> bf16 bits, RNE
  union { float f; unsigned int u; } c;
  c.f = v;
  return (ushortT)((c.u + 0x7fffu + ((c.u >> 16) & 1u)) >> 16);
}
__device__ __forceinline__ unsigned int pack2bf(float x, float y) {
  return (unsigned int)f2bu(x) | ((unsigned int)f2bu(y) << 16);
}
__device__ __forceinline__ ushortT f2h(float x) {
  _Float16 h = (_Float16)x;
  return __builtin_bit_cast(ushortT, h);
}
__device__ __forceinline__ float h2f(ushortT u) {
  return (float)__builtin_bit_cast(_Float16, u);
}

// Fused prep: blocks 0..95 = gate projection; blocks 96..351 = weight packing
// (q-columns pre-scaled by 1/sqrt(c_z)) + bias concat.
__global__ __launch_bounds__(256) void prep_kernel(
    const float* __restrict__ nf, const float* __restrict__ Wg, float* __restrict__ g,
    const float* __restrict__ Wqk, const float* __restrict__ bqk,
    const float* __restrict__ Wv, const float* __restrict__ bv,
    const float* __restrict__ Wout,
    ushortT* __restrict__ Wp1, ushortT* __restrict__ Wp2, float* __restrict__ bc) {
  int b = blockIdx.x, tid = threadIdx.x;
  if (b < 96) {
    int n = b * 4 + (tid >> 6), t = tid & 63;
    float a = nf[n * 128 + t];
    float bb = nf[n * 128 + 64 + t];
    float acc[8];
#pragma unroll
    for (int h = 0; h < 4; ++h) {
      acc[h]     = a * Wg[t * 4 + h]         + bb * Wg[(t + 64) * 4 + h];
      acc[4 + h] = a * Wg[(128 + t) * 4 + h] + bb * Wg[(192 + t) * 4 + h];
    }
#pragma unroll
    for (int i = 0; i < 8; ++i)
#pragma unroll
      for (int off = 32; off >= 1; off >>= 1) acc[i] += __shfl_xor(acc[i], off, 64);
    if (t == 0) {
#pragma unroll
      for (int i = 0; i < 8; ++i) g[n * 8 + i] = acc[i];
    }
  } else {
    int i = (b - 96) * 256 + tid;  // 65536 total
    if (i < 49152) {
      int j = i & 7, l = (i >> 3) & 63, t = (i >> 9) & 3;
      int nt = (i >> 11) % 12, ny = (i >> 11) / 12;
      int nn = ny * 192 + nt * 16 + (l & 15);
      int k = t * 32 + (l >> 4) * 8 + j;
      float v = (nn < 256) ? Wqk[k * 256 + nn] : Wv[k * 128 + (nn - 256)];
      if (nn < 128) v *= INV_SQRT_CZ;   // q columns pre-scaled
      Wp1[i] = f2bu(v);
    } else {
      int i2 = i - 49152;  // 16384
      int j = i2 & 7, l = (i2 >> 3) & 63, t = (i2 >> 9) & 3, nt = (i2 >> 11);
      int nn = nt * 16 + (l & 15);
      int k = t * 32 + (l >> 4) * 8 + j;
      Wp2[i2] = f2bu(Wout[k * 128 + nn]);
    }
    if (i < 384) {
      float v = (i < 256) ? bqk[i] : bv[i - 256];
      if (i < 128) v *= INV_SQRT_CZ;
      bc[i] = v;
    }
  }
}

// One block per node, 512 threads (8 waves, two 4-wave groups). Weights direct
// from global (L2-resident). Phase 2 gathers ei/nt/g from global (no phase-0
// staging, no barrier before it). kvb c-major conflict-free; single-pass softmax
// with packed-f32 (v_pk_fma) math; q pre-scaled in Wp1. Only 2 barriers.
__global__ __launch_bounds__(512, 4) void fused_kernel(
    const float* __restrict__ ef, const ushortT* __restrict__ Wp1,
    const ushortT* __restrict__ Wp2, const float* __restrict__ bc,
    const float* __restrict__ bout, const float* __restrict__ g,
    const float* __restrict__ node_trans, const int* __restrict__ edge_index,
    const int* __restrict__ sub_idx, const float* __restrict__ W_db,
    const float* __restrict__ b_db, const float* __restrict__ b_gate,
    float* __restrict__ outp) {
  __shared__ __align__(16) ushortT kvb[KNBR * 256];     // 30720 B
  __shared__ __align__(16) ushortT updq[64 * 136];      // 17408 B (q then upd)
  __shared__ __align__(16) ushortT biasb[KNBR * SUBK * 4];  // 9600 B, f16
  __shared__ ushortT sub_lds[KNBR * SUBK];              // 2400 B

  int n = blockIdx.x, tid = threadIdx.x;
  int e0 = n * KNBR;
  int w = tid >> 6, l = tid & 63;
  int lr = l & 15, lc = l >> 4;
  int rowA = (w & 3) * 16 + lr;          // 0..63 (rows 60..63 pad)
  int rowAc = min(rowA, KNBR - 1);
  int Tbase = (tid >> 8) * 12;

  // prefetch first B-tile (weight L2/HBM miss overlaps ef miss below)
  bf16x8 bcur[4], bnxt[4];
#pragma unroll
  for (int t = 0; t < 4; ++t)
    bcur[t] = *(const bf16x8*)(Wp1 + ((Tbase * 4 + t) * 64 + l) * 8);

  // A fragments from ef (f32 -> bf16)
  bf16x8 afrag[4];
#pragma unroll
  for (int t = 0; t < 4; ++t) {
    const float* ap = ef + (size_t)(e0 + rowAc) * 128 + t * 32 + lc * 8;
    float4 lo = *(const float4*)ap;
    float4 hi = *(const float4*)(ap + 4);
    bf16x8 a;
    a[0] = (short)f2bu(lo.x); a[1] = (short)f2bu(lo.y);
    a[2] = (short)f2bu(lo.z); a[3] = (short)f2bu(lo.w);
    a[4] = (short)f2bu(hi.x); a[5] = (short)f2bu(hi.y);
    a[6] = (short)f2bu(hi.z); a[7] = (short)f2bu(hi.w);
    afrag[t] = a;
  }

  // ---- phase 1: qkv projection, 12 tiles/group, prefetch-1 pipeline ----
#pragma unroll
  for (int Ti = 0; Ti < 12; ++Ti) {
    int T = Tbase + Ti;
    if (Ti < 11) {
#pragma unroll
      for (int t = 0; t < 4; ++t)
        bnxt[t] = *(const bf16x8*)(Wp1 + (((T + 1) * 4 + t) * 64 + l) * 8);
    }
    f32x4 acc = {0.f, 0.f, 0.f, 0.f};
#pragma unroll
    for (int t = 0; t < 4; ++t)
      acc = __builtin_amdgcn_mfma_f32_16x16x32_bf16(bcur[t], afrag[t], acc, 0, 0, 0);
    int col0 = T * 16 + lc * 4;
    float4 bi = *(const float4*)(bc + col0);
    float o0 = acc[0] + bi.x, o1 = acc[1] + bi.y;
    float o2 = acc[2] + bi.z, o3 = acc[3] + bi.w;
    uint2 o;
    o.x = pack2bf(o0, o1);
    o.y = pack2bf(o2, o3);
    if (T < 8) {  // q (pre-scaled) -> updq
      *(uint2*)(updq + rowA * 136 + col0) = o;
    } else if (rowA < KNBR) {  // k,v -> kvb (c-major, swizzled)
      int colk = col0 - 128;                  // 0..255
      int base_b = (colk & 128) << 1;         // 0 (K) or 256 (V)
      int d = colk & 127;
      int inner = ((d >> 3) & 1) * 128 + (((d >> 4) * 16) ^ ((rowA & 7) << 4)) + (d & 7) * 2;
      *(uint2*)((char*)kvb + rowA * 512 + base_b + inner) = o;
    }
#pragma unroll
    for (int t = 0; t < 4; ++t) bcur[t] = bnxt[t];
  }

  // ---- phase 2: bias precompute, all inputs gathered from global (L1/L2) ----
  float4 bgv = *(const float4*)b_gate;
  float4 bdbv = *(const float4*)b_db;
  for (int p = tid; p < KNBR * SUBK; p += 512) {
    int kl = p / SUBK, s = p - kl * SUBK;
    int j = sub_idx[(size_t)(e0 + kl) * SUBK + s];
    sub_lds[p] = (ushortT)j;
    int dk = edge_index[e0 + kl];
    int dj = edge_index[e0 + j];
    float dx = node_trans[dk * 3 + 0] - node_trans[dj * 3 + 0] + EPSC;
    float dy = node_trans[dk * 3 + 1] - node_trans[dj * 3 + 1] + EPSC;
    float dz = node_trans[dk * 3 + 2] - node_trans[dj * 3 + 2] + EPSC;
    float dist = sqrtf(dx * dx + dy * dy + dz * dz);
    int r0 = (int)(dist * INV_MU_STEP + 0.5f);
    int rlo = max(r0 - 4, 0), rhi = min(r0 + 4, 63);
    float a0 = 0.f, a1 = 0.f, a2 = 0.f, a3 = 0.f;
    for (int r = rlo; r <= rhi; ++r) {
      float t = (dist - r * MU_STEP) * INV_SIGMA;
      float e = __expf(-t * t);
      float4 wv = ((const float4*)W_db)[r];
      a0 += e * wv.x; a1 += e * wv.y; a2 += e * wv.z; a3 += e * wv.w;
    }
    float4 gk = *(const float4*)(g + dk * 8);       // g1(dk)
    float4 gj = *(const float4*)(g + dj * 8 + 4);   // g2(dj)
    float g1 = gk.x + gj.x + bgv.x;
    float g2 = gk.y + gj.y + bgv.y;
    float g3 = gk.z + gj.z + bgv.z;
    float g4 = gk.w + gj.w + bgv.w;
    biasb[p * 4 + 0] = f2h((a0 + bdbv.x) / (1.0f + __expf(-g1)));
    biasb[p * 4 + 1] = f2h((a1 + bdbv.y) / (1.0f + __expf(-g2)));
    biasb[p * 4 + 2] = f2h((a2 + bdbv.z) / (1.0f + __expf(-g3)));
    biasb[p * 4 + 3] = f2h((a3 + bdbv.w) / (1.0f + __expf(-g4)));
  }
  __syncthreads();  // barrier 1: kvb + q(updq) + biasb + sub_lds visible

  // ---- phase 3: attention, single pass, packed-f32 math ----
  int row3 = tid >> 3, h = (tid >> 1) & 3, dh = tid & 1;
  int row3c = min(row3, KNBR - 1);
  int hdo = (h * 2 + dh) * 16;
  const char* kvbase = (const char*)kvb;
  f32x2 qv0, qv1, qv2, qv3, qv4, qv5, qv6, qv7;
  {
    const ushortT* qp = updq + row3 * 136 + h * 32 + dh * 16;
    uint4 u0 = *(const uint4*)qp;
    uint4 u1 = *(const uint4*)(qp + 8);
    qv0 = bfpair(u0.x); qv1 = bfpair(u0.y); qv2 = bfpair(u0.z); qv3 = bfpair(u0.w);
    qv4 = bfpair(u1.x); qv5 = bfpair(u1.y); qv6 = bfpair(u1.z); qv7 = bfpair(u1.w);
  }
  float den = 0.f;
  f32x2 va0 = {0.f, 0.f}, va1 = {0.f, 0.f}, va2 = {0.f, 0.f}, va3 = {0.f, 0.f};
  f32x2 va4 = {0.f, 0.f}, va5 = {0.f, 0.f}, va6 = {0.f, 0.f}, va7 = {0.f, 0.f};
#pragma unroll 4
  for (int s = 0; s < SUBK; ++s) {
    int j = sub_lds[row3c * SUBK + s];
    int off = hdo ^ ((j & 7) << 4);
    const char* kr = kvbase + j * 512;
    uint4 k0 = *(const uint4*)(kr + off);
    uint4 k1 = *(const uint4*)(kr + 128 + off);
    f32x2 dacc = qv0 * bfpair(k0.x);
    dacc += qv1 * bfpair(k0.y);
    dacc += qv2 * bfpair(k0.z);
    dacc += qv3 * bfpair(k0.w);
    dacc += qv4 * bfpair(k1.x);
    dacc += qv5 * bfpair(k1.y);
    dacc += qv6 * bfpair(k1.z);
    dacc += qv7 * bfpair(k1.w);
    float dot = dacc.x + dacc.y;
    dot += __shfl_xor(dot, 1);
    float p = __expf(dot + h2f(biasb[(row3c * SUBK + s) * 4 + h]));
    den += p;
    f32x2 pp = {p, p};
    uint4 w0 = *(const uint4*)(kr + 256 + off);
    uint4 w1 = *(const uint4*)(kr + 384 + off);
    va0 += pp * bfpair(w0.x);
    va1 += pp * bfpair(w0.y);
    va2 += pp * bfpair(w0.z);
    va3 += pp * bfpair(w0.w);
    va4 += pp * bfpair(w1.x);
    va5 += pp * bfpair(w1.y);
    va6 += pp * bfpair(w1.z);
    va7 += pp * bfpair(w1.w);
  }
  float inv = 1.0f / den;
  {
    uint4 o;
    o.x = pack2bf(va0.x * inv, va0.y * inv);
    o.y = pack2bf(va1.x * inv, va1.y * inv);
    o.z = pack2bf(va2.x * inv, va2.y * inv);
    o.w = pack2bf(va3.x * inv, va3.y * inv);
    *(uint4*)(updq + row3 * 136 + h * 32 + dh * 16) = o;
    uint4 o2;
    o2.x = pack2bf(va4.x * inv, va4.y * inv);
    o2.y = pack2bf(va5.x * inv, va5.y * inv);
    o2.z = pack2bf(va6.x * inv, va6.y * inv);
    o2.w = pack2bf(va7.x * inv, va7.y * inv);
    *(uint4*)(updq + row3 * 136 + h * 32 + dh * 16 + 8) = o2;
  }
  __syncthreads();  // barrier 2: upd visible

  // ---- phase 4: out projection, 4 tiles/group, prefetch-1 pipeline ----
  int T4base = (tid >> 8) * 4;
  bf16x8 af2[4];
#pragma unroll
  for (int t = 0; t < 4; ++t)
    af2[t] = *(const bf16x8*)(updq + rowA * 136 + t * 32 + lc * 8);
  bf16x8 c2[4], n2[4];
#pragma unroll
  for (int t = 0; t < 4; ++t)
    c2[t] = *(const bf16x8*)(Wp2 + ((T4base * 4 + t) * 64 + l) * 8);
#pragma unroll
  for (int Ti = 0; Ti < 4; ++Ti) {
    int T = T4base + Ti;
    if (Ti < 3) {
#pragma unroll
      for (int t = 0; t < 4; ++t)
        n2[t] = *(const bf16x8*)(Wp2 + (((T + 1) * 4 + t) * 64 + l) * 8);
    }
    f32x4 acc = {0.f, 0.f, 0.f, 0.f};
#pragma unroll
    for (int t = 0; t < 4; ++t)
      acc = __builtin_amdgcn_mfma_f32_16x16x32_bf16(c2[t], af2[t], acc, 0, 0, 0);
    if (rowA < KNBR) {
      int col0 = T * 16 + lc * 4;
      float4 bi = *(const float4*)(bout + col0);
      float4 o;
      o.x = acc[0] + bi.x; o.y = acc[1] + bi.y;
      o.z = acc[2] + bi.z; o.w = acc[3] + bi.w;
      *(float4*)(outp + (size_t)(e0 + rowA) * 128 + col0) = o;
    }
#pragma unroll
    for (int t = 0; t < 4; ++t) c2[t] = n2[t];
  }
}

extern "C" void kernel_launch(void* const* d_in, const int* in_sizes, int n_in, void* d_out,
                              int out_size, void* d_ws, size_t ws_size, hipStream_t stream) {
  const float* nf  = (const float*)d_in[0];
  const float* nt  = (const float*)d_in[1];
  const float* ef  = (const float*)d_in[2];
  const int*   ei  = (const int*)d_in[3];
  const int*   si  = (const int*)d_in[4];
  const float* Wg  = (const float*)d_in[5];
  const float* bg  = (const float*)d_in[6];
  const float* Wdb = (const float*)d_in[7];
  const float* bdb = (const float*)d_in[8];
  const float* Wqk = (const float*)d_in[9];
  const float* bqk = (const float*)d_in[10];
  const float* Wv  = (const float*)d_in[11];
  const float* bv  = (const float*)d_in[12];
  const float* Wout = (const float*)d_in[13];
  const float* bout = (const float*)d_in[14];
  float* out = (float*)d_out;  // f32 output

  float* g      = (float*)d_ws;                 // 3072 f32
  float* bc     = g + 3072;                     // 384 f32
  ushortT* Wp1  = (ushortT*)(bc + 384);         // 49152 bf16
  ushortT* Wp2  = Wp1 + 49152;                  // 16384 bf16

  prep_kernel<<<dim3(352), dim3(256), 0, stream>>>(nf, Wg, g, Wqk, bqk, Wv, bv, Wout,
                                                   Wp1, Wp2, bc);
  fused_kernel<<<dim3(N_NODES), dim3(512), 0, stream>>>(ef, Wp1, Wp2, bc, bout, g, nt, ei, si,
                                                        Wdb, bdb, bg, out);
}